// Round 2
// baseline (1303.025 us; speedup 1.0000x reference)
//
#include <hip/hip_runtime.h>
#include <stdint.h>

#define BATCH 8
#define NPTS 8192
#define NGRP 512
#define GSZ 32

// ((dx*dx + dy*dy) + dz*dz), sequential, round-to-nearest, NO fma contraction —
// matches XLA-CPU strict elementwise square + sequential axis-sum.
__device__ __forceinline__ float sq3(float dx, float dy, float dz) {
    return __fadd_rn(__fadd_rn(__fmul_rn(dx, dx), __fmul_rn(dy, dy)), __fmul_rn(dz, dz));
}

// ---------------------------------------------------------------------------
// FPS: one block per batch, 512 threads, 16 points/thread held in registers.
// 511 sequential steps: block-wide argmax (value desc, index asc on ties),
// then d = min(d, dist2(p, newp)).
// ---------------------------------------------------------------------------
__global__ __launch_bounds__(512) void fps_kernel(const float* __restrict__ xyz,
                                                  float* __restrict__ centers) {
    const int b = blockIdx.x;
    const int tid = threadIdx.x;
    const int lane = tid & 63;
    const int wv = tid >> 6;  // 0..7

    __shared__ float rv[8], rx[8], ry[8], rz[8];
    __shared__ int rp[8];

    float px[16], py[16], pz[16], d[16];
    const float* base = xyz + (size_t)b * NPTS * 6;
    const float x0 = base[0], y0 = base[1], z0 = base[2];

#pragma unroll
    for (int i = 0; i < 16; ++i) {
        const int p = i * 512 + tid;
        const float* q = base + (size_t)p * 6;
        px[i] = q[0]; py[i] = q[1]; pz[i] = q[2];
        d[i] = sq3(__fsub_rn(px[i], x0), __fsub_rn(py[i], y0), __fsub_rn(pz[i], z0));
    }
    if (tid == 0) {
        float* c = centers + ((size_t)b * NGRP) * 3;
        c[0] = x0; c[1] = y0; c[2] = z0;
    }

    for (int k = 1; k < NGRP; ++k) {
        // local argmax; slots ascend in global index, strict '>' keeps lowest idx
        float bv = d[0]; int bp = tid;
        float bx = px[0], by = py[0], bz = pz[0];
#pragma unroll
        for (int i = 1; i < 16; ++i) {
            if (d[i] > bv) { bv = d[i]; bp = i * 512 + tid; bx = px[i]; by = py[i]; bz = pz[i]; }
        }
        // wave (64-lane) argmax reduce, carrying winning coords along
#pragma unroll
        for (int off = 32; off >= 1; off >>= 1) {
            float ov = __shfl_xor(bv, off);
            int   op = __shfl_xor(bp, off);
            float ox = __shfl_xor(bx, off);
            float oy = __shfl_xor(by, off);
            float oz = __shfl_xor(bz, off);
            if (ov > bv || (ov == bv && op < bp)) { bv = ov; bp = op; bx = ox; by = oy; bz = oz; }
        }
        if (lane == 0) { rv[wv] = bv; rp[wv] = bp; rx[wv] = bx; ry[wv] = by; rz[wv] = bz; }
        __syncthreads();
        // cross-wave reduce (8 entries), identical on every thread
        float Bv = rv[0]; int Bp = rp[0];
        float Bx = rx[0], By = ry[0], Bz = rz[0];
#pragma unroll
        for (int w = 1; w < 8; ++w) {
            const float v = rv[w]; const int p = rp[w];
            if (v > Bv || (v == Bv && p < Bp)) { Bv = v; Bp = p; Bx = rx[w]; By = ry[w]; Bz = rz[w]; }
        }
        __syncthreads();  // LDS reuse guard for next iteration
        // distance update against new center
#pragma unroll
        for (int i = 0; i < 16; ++i) {
            const float nd = sq3(__fsub_rn(px[i], Bx), __fsub_rn(py[i], By), __fsub_rn(pz[i], Bz));
            d[i] = fminf(d[i], nd);
        }
        if (tid == 0) {
            float* c = centers + ((size_t)b * NGRP + k) * 3;
            c[0] = Bx; c[1] = By; c[2] = Bz;
        }
    }
}

// ---------------------------------------------------------------------------
// KNN + gather: one block (256 threads) per (batch, group) row.
// d2 = (c2 - 2*dot) + x2 exactly as the reference's expanded form.
// dot uses a sequential FMA chain (k=0,1,2) to match the GEMM lowering of
// einsum('bgd,bnd->bgn') on the reference backend: acc = fma(c_k, x_k, acc).
// 32 rounds of block-wide 64-bit argmin with (d2bits|idx) keys => sorted,
// tie -> lower index, matching lax.top_k.
// ---------------------------------------------------------------------------
__global__ __launch_bounds__(256) void knn_kernel(const float* __restrict__ xyz,
                                                  const float* __restrict__ centers,
                                                  float* __restrict__ neigh,
                                                  float* __restrict__ neigh_n) {
    const int row = blockIdx.x;   // b*NGRP + g
    const int b = row >> 9;
    const int tid = threadIdx.x;
    const int lane = tid & 63;
    const int wv = tid >> 6;  // 0..3

    __shared__ unsigned long long rk[4];
    __shared__ int sel[GSZ];

    const float* cptr = centers + (size_t)row * 3;
    const float cx = cptr[0], cy = cptr[1], cz = cptr[2];
    const float c2 = sq3(cx, cy, cz);

    const float* base = xyz + (size_t)b * NPTS * 6;
    unsigned long long key[32];
#pragma unroll
    for (int i = 0; i < 32; ++i) {
        const int p = i * 256 + tid;
        const float* q = base + (size_t)p * 6;
        const float x = q[0], y = q[1], z = q[2];
        const float x2 = sq3(x, y, z);
        // GEMM-style FMA accumulation over k = x,y,z
        const float dot = __fmaf_rn(cz, z, __fmaf_rn(cy, y, __fmul_rn(cx, x)));
        const float d2 = __fadd_rn(__fsub_rn(c2, __fmul_rn(2.0f, dot)), x2);
        // monotonic float->uint transform (handles negative-from-rounding d2)
        unsigned u = __float_as_uint(d2);
        u = (u & 0x80000000u) ? ~u : (u | 0x80000000u);
        key[i] = ((unsigned long long)u << 32) | (unsigned)p;
    }

    for (int r = 0; r < GSZ; ++r) {
        unsigned long long mk = key[0];
#pragma unroll
        for (int i = 1; i < 32; ++i) mk = key[i] < mk ? key[i] : mk;
#pragma unroll
        for (int off = 32; off >= 1; off >>= 1) {
            const unsigned long long ok = __shfl_xor(mk, off);
            mk = ok < mk ? ok : mk;
        }
        if (lane == 0) rk[wv] = mk;
        __syncthreads();
        const unsigned long long g01 = rk[0] < rk[1] ? rk[0] : rk[1];
        const unsigned long long g23 = rk[2] < rk[3] ? rk[2] : rk[3];
        const unsigned long long gm = g01 < g23 ? g01 : g23;
        if (tid == 0) sel[r] = (int)(unsigned)(gm & 0xffffffffu);
        // remove winner (keys are unique; static per-slot conditional, stays in regs)
#pragma unroll
        for (int i = 0; i < 32; ++i) {
            if (key[i] == gm) key[i] = ~0ULL;
        }
        __syncthreads();
    }

    if (tid < GSZ) {
        const int idx = sel[tid];
        const float* q = base + (size_t)idx * 6;
        const size_t o = ((size_t)row * GSZ + tid) * 3;
        neigh[o + 0] = __fsub_rn(q[0], cx);
        neigh[o + 1] = __fsub_rn(q[1], cy);
        neigh[o + 2] = __fsub_rn(q[2], cz);
        neigh_n[o + 0] = q[3];
        neigh_n[o + 1] = q[4];
        neigh_n[o + 2] = q[5];
    }
}

extern "C" void kernel_launch(void* const* d_in, const int* in_sizes, int n_in,
                              void* d_out, int out_size, void* d_ws, size_t ws_size,
                              hipStream_t stream) {
    const float* xyz = (const float*)d_in[0];
    float* out = (float*)d_out;
    float* neigh   = out;                                   // [8,512,32,3]
    float* neigh_n = out + (size_t)BATCH * NGRP * GSZ * 3;  // [8,512,32,3]
    float* centers = out + (size_t)2 * BATCH * NGRP * GSZ * 3;  // [8,512,3]

    fps_kernel<<<BATCH, 512, 0, stream>>>(xyz, centers);
    knn_kernel<<<BATCH * NGRP, 256, 0, stream>>>(xyz, centers, neigh, neigh_n);
}

// Round 3
// 1256.698 us; speedup vs baseline: 1.0369x; 1.0369x over previous
//
#include <hip/hip_runtime.h>
#include <stdint.h>

#define BATCH 8
#define NPTS 8192
#define NGRP 512
#define GSZ 32

// ((dx*dx + dy*dy) + dz*dz), sequential, round-to-nearest, NO fma contraction —
// matches XLA-CPU strict elementwise square + sequential axis-sum.
__device__ __forceinline__ float sq3(float dx, float dy, float dz) {
    return __fadd_rn(__fadd_rn(__fmul_rn(dx, dx), __fmul_rn(dy, dy)), __fmul_rn(dz, dz));
}

// ---------------------------------------------------------------------------
// FPS: one block per batch, 1024 threads, 8 points/thread in registers.
// Per step (fused): d = min(d, dist2(p, B)); key = (fbits(d)<<13)|(8191-idx);
// depth-3 local tree -> 6-round wave max-reduce (carrying coords) ->
// LDS (double-buffered, ONE barrier) -> depth-4 cross-wave key tree ->
// winning wave decoded from key low bits -> coords from its LDS slot.
// Exact: d >= 0 so float bits are order-monotonic; max over (8191-idx)
// breaks ties toward the LOWEST index, matching jnp.argmax.
// ---------------------------------------------------------------------------
__global__ __launch_bounds__(1024) void fps_kernel(const float* __restrict__ xyz,
                                                   float* __restrict__ centers) {
    const int b = blockIdx.x;
    const int tid = threadIdx.x;
    const int lane = tid & 63;
    const int wv = tid >> 6;  // 0..15

    __shared__ unsigned long long skey[2][16];
    __shared__ float sx[2][16], sy[2][16], sz[2][16];

    float px[8], py[8], pz[8], d[8];
    unsigned lowbits[8];
    const float* base = xyz + (size_t)b * NPTS * 6;

#pragma unroll
    for (int i = 0; i < 8; ++i) {
        const int p = i * 1024 + tid;
        const float* q = base + (size_t)p * 6;
        px[i] = q[0]; py[i] = q[1]; pz[i] = q[2];
        d[i] = __int_as_float(0x7f800000);  // +inf: first update yields dist-to-point0
        lowbits[i] = (unsigned)(8191 - p);
    }
    float Bx = base[0], By = base[1], Bz = base[2];
    if (tid == 0) {
        float* c = centers + (size_t)b * NGRP * 3;
        c[0] = Bx; c[1] = By; c[2] = Bz;
    }

    for (int k = 1; k < NGRP; ++k) {
        // ---- fused distance update + key build ----
        unsigned long long kk[8];
#pragma unroll
        for (int i = 0; i < 8; ++i) {
            const float nd = sq3(__fsub_rn(px[i], Bx), __fsub_rn(py[i], By), __fsub_rn(pz[i], Bz));
            d[i] = fminf(d[i], nd);
            kk[i] = ((unsigned long long)__float_as_uint(d[i]) << 13) | lowbits[i];
        }
        // ---- depth-3 local max tree, carrying coords (keys unique) ----
        const bool c01 = kk[0] > kk[1];
        unsigned long long k01 = c01 ? kk[0] : kk[1];
        float x01 = c01 ? px[0] : px[1], y01 = c01 ? py[0] : py[1], z01 = c01 ? pz[0] : pz[1];
        const bool c23 = kk[2] > kk[3];
        unsigned long long k23 = c23 ? kk[2] : kk[3];
        float x23 = c23 ? px[2] : px[3], y23 = c23 ? py[2] : py[3], z23 = c23 ? pz[2] : pz[3];
        const bool c45 = kk[4] > kk[5];
        unsigned long long k45 = c45 ? kk[4] : kk[5];
        float x45 = c45 ? px[4] : px[5], y45 = c45 ? py[4] : py[5], z45 = c45 ? pz[4] : pz[5];
        const bool c67 = kk[6] > kk[7];
        unsigned long long k67 = c67 ? kk[6] : kk[7];
        float x67 = c67 ? px[6] : px[7], y67 = c67 ? py[6] : py[7], z67 = c67 ? pz[6] : pz[7];
        const bool ca = k01 > k23;
        unsigned long long ka = ca ? k01 : k23;
        float xa = ca ? x01 : x23, ya = ca ? y01 : y23, za = ca ? z01 : z23;
        const bool cb = k45 > k67;
        unsigned long long kb = cb ? k45 : k67;
        float xb = cb ? x45 : x67, yb = cb ? y45 : y67, zb = cb ? z45 : z67;
        const bool cf = ka > kb;
        unsigned long long lk = cf ? ka : kb;
        float lx = cf ? xa : xb, ly = cf ? ya : yb, lz = cf ? za : zb;

        // ---- wave (64-lane) max reduce, carrying coords ----
#pragma unroll
        for (int off = 32; off >= 1; off >>= 1) {
            const unsigned long long ok = __shfl_xor(lk, off);
            const float ox = __shfl_xor(lx, off);
            const float oy = __shfl_xor(ly, off);
            const float oz = __shfl_xor(lz, off);
            if (ok > lk) { lk = ok; lx = ox; ly = oy; lz = oz; }
        }

        // ---- cross-wave via double-buffered LDS, ONE barrier ----
        const int buf = k & 1;
        if (lane == 0) { skey[buf][wv] = lk; sx[buf][wv] = lx; sy[buf][wv] = ly; sz[buf][wv] = lz; }
        __syncthreads();

        unsigned long long t0  = skey[buf][0],  t1  = skey[buf][1],  t2  = skey[buf][2],  t3  = skey[buf][3];
        unsigned long long t4  = skey[buf][4],  t5  = skey[buf][5],  t6  = skey[buf][6],  t7  = skey[buf][7];
        unsigned long long t8  = skey[buf][8],  t9  = skey[buf][9],  t10 = skey[buf][10], t11 = skey[buf][11];
        unsigned long long t12 = skey[buf][12], t13 = skey[buf][13], t14 = skey[buf][14], t15 = skey[buf][15];
        unsigned long long m0 = t0 > t1 ? t0 : t1;
        unsigned long long m1 = t2 > t3 ? t2 : t3;
        unsigned long long m2 = t4 > t5 ? t4 : t5;
        unsigned long long m3 = t6 > t7 ? t6 : t7;
        unsigned long long m4 = t8 > t9 ? t8 : t9;
        unsigned long long m5 = t10 > t11 ? t10 : t11;
        unsigned long long m6 = t12 > t13 ? t12 : t13;
        unsigned long long m7 = t14 > t15 ? t14 : t15;
        m0 = m0 > m1 ? m0 : m1;
        m2 = m2 > m3 ? m2 : m3;
        m4 = m4 > m5 ? m4 : m5;
        m6 = m6 > m7 ? m6 : m7;
        m0 = m0 > m2 ? m0 : m2;
        m4 = m4 > m6 ? m4 : m6;
        const unsigned long long gk = m0 > m4 ? m0 : m4;

        // decode winner: key low 13 bits = 8191 - idx; owning wave = (idx & 1023) >> 6
        const int widx = 8191 - (int)((unsigned)gk & 8191u);
        const int bwv = (widx & 1023) >> 6;
        Bx = sx[buf][bwv]; By = sy[buf][bwv]; Bz = sz[buf][bwv];

        if (tid == 0) {
            float* c = centers + ((size_t)b * NGRP + k) * 3;
            c[0] = Bx; c[1] = By; c[2] = Bz;
        }
    }
}

// ---------------------------------------------------------------------------
// KNN + gather: one block (256 threads) per (batch, group) row. (unchanged,
// known-exact: FMA-chain dot matching the reference GEMM, u64 argmin rounds)
// ---------------------------------------------------------------------------
__global__ __launch_bounds__(256) void knn_kernel(const float* __restrict__ xyz,
                                                  const float* __restrict__ centers,
                                                  float* __restrict__ neigh,
                                                  float* __restrict__ neigh_n) {
    const int row = blockIdx.x;   // b*NGRP + g
    const int b = row >> 9;
    const int tid = threadIdx.x;
    const int lane = tid & 63;
    const int wv = tid >> 6;  // 0..3

    __shared__ unsigned long long rk[4];
    __shared__ int sel[GSZ];

    const float* cptr = centers + (size_t)row * 3;
    const float cx = cptr[0], cy = cptr[1], cz = cptr[2];
    const float c2 = sq3(cx, cy, cz);

    const float* base = xyz + (size_t)b * NPTS * 6;
    unsigned long long key[32];
#pragma unroll
    for (int i = 0; i < 32; ++i) {
        const int p = i * 256 + tid;
        const float* q = base + (size_t)p * 6;
        const float x = q[0], y = q[1], z = q[2];
        const float x2 = sq3(x, y, z);
        // GEMM-style FMA accumulation over k = x,y,z
        const float dot = __fmaf_rn(cz, z, __fmaf_rn(cy, y, __fmul_rn(cx, x)));
        const float d2 = __fadd_rn(__fsub_rn(c2, __fmul_rn(2.0f, dot)), x2);
        // monotonic float->uint transform (handles negative-from-rounding d2)
        unsigned u = __float_as_uint(d2);
        u = (u & 0x80000000u) ? ~u : (u | 0x80000000u);
        key[i] = ((unsigned long long)u << 32) | (unsigned)p;
    }

    for (int r = 0; r < GSZ; ++r) {
        unsigned long long mk = key[0];
#pragma unroll
        for (int i = 1; i < 32; ++i) mk = key[i] < mk ? key[i] : mk;
#pragma unroll
        for (int off = 32; off >= 1; off >>= 1) {
            const unsigned long long ok = __shfl_xor(mk, off);
            mk = ok < mk ? ok : mk;
        }
        if (lane == 0) rk[wv] = mk;
        __syncthreads();
        const unsigned long long g01 = rk[0] < rk[1] ? rk[0] : rk[1];
        const unsigned long long g23 = rk[2] < rk[3] ? rk[2] : rk[3];
        const unsigned long long gm = g01 < g23 ? g01 : g23;
        if (tid == 0) sel[r] = (int)(unsigned)(gm & 0xffffffffu);
        // remove winner (keys are unique; static per-slot conditional, stays in regs)
#pragma unroll
        for (int i = 0; i < 32; ++i) {
            if (key[i] == gm) key[i] = ~0ULL;
        }
        __syncthreads();
    }

    if (tid < GSZ) {
        const int idx = sel[tid];
        const float* q = base + (size_t)idx * 6;
        const size_t o = ((size_t)row * GSZ + tid) * 3;
        neigh[o + 0] = __fsub_rn(q[0], cx);
        neigh[o + 1] = __fsub_rn(q[1], cy);
        neigh[o + 2] = __fsub_rn(q[2], cz);
        neigh_n[o + 0] = q[3];
        neigh_n[o + 1] = q[4];
        neigh_n[o + 2] = q[5];
    }
}

extern "C" void kernel_launch(void* const* d_in, const int* in_sizes, int n_in,
                              void* d_out, int out_size, void* d_ws, size_t ws_size,
                              hipStream_t stream) {
    const float* xyz = (const float*)d_in[0];
    float* out = (float*)d_out;
    float* neigh   = out;                                   // [8,512,32,3]
    float* neigh_n = out + (size_t)BATCH * NGRP * GSZ * 3;  // [8,512,32,3]
    float* centers = out + (size_t)2 * BATCH * NGRP * GSZ * 3;  // [8,512,3]

    fps_kernel<<<BATCH, 1024, 0, stream>>>(xyz, centers);
    knn_kernel<<<BATCH * NGRP, 256, 0, stream>>>(xyz, centers, neigh, neigh_n);
}

// Round 4
// 1005.183 us; speedup vs baseline: 1.2963x; 1.2502x over previous
//
#include <hip/hip_runtime.h>
#include <stdint.h>

#define BATCH 8
#define NPTS 8192
#define NGRP 512
#define GSZ 32

// ((dx*dx + dy*dy) + dz*dz), sequential, round-to-nearest, NO fma contraction —
// matches XLA-CPU strict elementwise square + sequential axis-sum.
__device__ __forceinline__ float sq3(float dx, float dy, float dz) {
    return __fadd_rn(__fadd_rn(__fmul_rn(dx, dx), __fmul_rn(dy, dy)), __fmul_rn(dz, dz));
}

// ---------------------------------------------------------------------------
// FPS: one block per batch, 1024 threads, 8 points/thread in registers.
// Per step: d=min(d,dist2); key=(fbits(d)<<13)|(8191-idx); local coord-carrying
// tree (7 sel) -> 4 KEY-ONLY xor rounds within 16-lane groups -> unique owner
// (myKey==groupMax) writes key+coords to 1 of 64 partial slots -> barrier ->
// wave0 reduces 64 partials (6 coord-carrying rounds), lane0 posts coords to
// bcast -> barrier -> all read 3 floats. tid0 writes centers AFTER barrier2.
// Exact: d>=0 => float bits order-monotonic; max over (8191-idx) breaks ties
// toward LOWEST index, matching jnp.argmax. Keys unique => owner unique.
// ---------------------------------------------------------------------------
__global__ __launch_bounds__(1024) void fps_kernel(const float* __restrict__ xyz,
                                                   float* __restrict__ centers) {
    const int b = blockIdx.x;
    const int tid = threadIdx.x;
    const int lane = tid & 63;

    __shared__ unsigned long long pkey[64];
    __shared__ float pxyz[64][4];
    __shared__ float bcast[4];

    float px[8], py[8], pz[8], d[8];
    unsigned lowbits[8];
    const float* base = xyz + (size_t)b * NPTS * 6;

#pragma unroll
    for (int i = 0; i < 8; ++i) {
        const int p = i * 1024 + tid;
        const float* q = base + (size_t)p * 6;
        px[i] = q[0]; py[i] = q[1]; pz[i] = q[2];
        d[i] = __int_as_float(0x7f800000);  // +inf: first update = dist-to-point0
        lowbits[i] = (unsigned)(8191 - p);
    }
    float Bx = base[0], By = base[1], Bz = base[2];
    if (tid == 0) {
        float* c = centers + (size_t)b * NGRP * 3;
        c[0] = Bx; c[1] = By; c[2] = Bz;
    }

    for (int k = 1; k < NGRP; ++k) {
        // ---- fused distance update + key build ----
        unsigned long long kk[8];
#pragma unroll
        for (int i = 0; i < 8; ++i) {
            const float nd = sq3(__fsub_rn(px[i], Bx), __fsub_rn(py[i], By), __fsub_rn(pz[i], Bz));
            d[i] = fminf(d[i], nd);
            kk[i] = ((unsigned long long)__float_as_uint(d[i]) << 13) | lowbits[i];
        }
        // ---- depth-3 local max tree, carrying coords (keys unique) ----
        const bool c01 = kk[0] > kk[1];
        unsigned long long k01 = c01 ? kk[0] : kk[1];
        float x01 = c01 ? px[0] : px[1], y01 = c01 ? py[0] : py[1], z01 = c01 ? pz[0] : pz[1];
        const bool c23 = kk[2] > kk[3];
        unsigned long long k23 = c23 ? kk[2] : kk[3];
        float x23 = c23 ? px[2] : px[3], y23 = c23 ? py[2] : py[3], z23 = c23 ? pz[2] : pz[3];
        const bool c45 = kk[4] > kk[5];
        unsigned long long k45 = c45 ? kk[4] : kk[5];
        float x45 = c45 ? px[4] : px[5], y45 = c45 ? py[4] : py[5], z45 = c45 ? pz[4] : pz[5];
        const bool c67 = kk[6] > kk[7];
        unsigned long long k67 = c67 ? kk[6] : kk[7];
        float x67 = c67 ? px[6] : px[7], y67 = c67 ? py[6] : py[7], z67 = c67 ? pz[6] : pz[7];
        const bool ca = k01 > k23;
        unsigned long long ka = ca ? k01 : k23;
        float xa = ca ? x01 : x23, ya = ca ? y01 : y23, za = ca ? z01 : z23;
        const bool cb = k45 > k67;
        unsigned long long kb = cb ? k45 : k67;
        float xb = cb ? x45 : x67, yb = cb ? y45 : y67, zb = cb ? z45 : z67;
        const bool cf = ka > kb;
        const unsigned long long myk = cf ? ka : kb;
        const float lx = cf ? xa : xb, ly = cf ? ya : yb, lz = cf ? za : zb;

        // ---- 4 KEY-ONLY xor rounds within 16-lane groups ----
        unsigned long long gk = myk;
#pragma unroll
        for (int off = 8; off >= 1; off >>= 1) {
            const unsigned long long ok = __shfl_xor(gk, off);
            gk = ok > gk ? ok : gk;
        }
        // unique owner of the group max writes the partial slot
        if (myk == gk) {
            const int slot = tid >> 4;
            pkey[slot] = myk;
            pxyz[slot][0] = lx; pxyz[slot][1] = ly; pxyz[slot][2] = lz;
        }
        __syncthreads();

        // ---- wave0 reduces the 64 partials, carrying coords ----
        if (tid < 64) {
            unsigned long long wk = pkey[lane];
            float wx = pxyz[lane][0], wy = pxyz[lane][1], wz = pxyz[lane][2];
#pragma unroll
            for (int off = 32; off >= 1; off >>= 1) {
                const unsigned long long ok = __shfl_xor(wk, off);
                const float ox = __shfl_xor(wx, off);
                const float oy = __shfl_xor(wy, off);
                const float oz = __shfl_xor(wz, off);
                if (ok > wk) { wk = ok; wx = ox; wy = oy; wz = oz; }
            }
            if (lane == 0) { bcast[0] = wx; bcast[1] = wy; bcast[2] = wz; }
        }
        __syncthreads();

        Bx = bcast[0]; By = bcast[1]; Bz = bcast[2];
        if (tid == 0) {  // off the critical path: store after barrier2
            float* c = centers + ((size_t)b * NGRP + k) * 3;
            c[0] = Bx; c[1] = By; c[2] = Bz;
        }
    }
}

// ---------------------------------------------------------------------------
// KNN + gather: one block (256 threads) per (batch, group) row.
// FP identical to the passing version (FMA-chain dot matching the reference
// GEMM). Selection: cached local-min `lm` per thread; per round only the
// unique owner (lm==gm) rescans/removes/recomputes. rk double-buffered =>
// one barrier per round.
// ---------------------------------------------------------------------------
__global__ __launch_bounds__(256) void knn_kernel(const float* __restrict__ xyz,
                                                  const float* __restrict__ centers,
                                                  float* __restrict__ neigh,
                                                  float* __restrict__ neigh_n) {
    const int row = blockIdx.x;   // b*NGRP + g
    const int b = row >> 9;
    const int tid = threadIdx.x;
    const int lane = tid & 63;
    const int wv = tid >> 6;  // 0..3

    __shared__ unsigned long long rk[2][4];
    __shared__ int sel[GSZ];

    const float* cptr = centers + (size_t)row * 3;
    const float cx = cptr[0], cy = cptr[1], cz = cptr[2];
    const float c2 = sq3(cx, cy, cz);

    const float* base = xyz + (size_t)b * NPTS * 6;
    unsigned long long key[32];
#pragma unroll
    for (int i = 0; i < 32; ++i) {
        const int p = i * 256 + tid;
        const float* q = base + (size_t)p * 6;
        const float x = q[0], y = q[1], z = q[2];
        const float x2 = sq3(x, y, z);
        // GEMM-style FMA accumulation over k = x,y,z
        const float dot = __fmaf_rn(cz, z, __fmaf_rn(cy, y, __fmul_rn(cx, x)));
        const float d2 = __fadd_rn(__fsub_rn(c2, __fmul_rn(2.0f, dot)), x2);
        // monotonic float->uint transform (handles negative-from-rounding d2)
        unsigned u = __float_as_uint(d2);
        u = (u & 0x80000000u) ? ~u : (u | 0x80000000u);
        key[i] = ((unsigned long long)u << 32) | (unsigned)p;
    }

    // cached local min over this thread's 32 keys
    unsigned long long lm = key[0];
#pragma unroll
    for (int i = 1; i < 32; ++i) lm = key[i] < lm ? key[i] : lm;

    for (int r = 0; r < GSZ; ++r) {
        unsigned long long mk = lm;
#pragma unroll
        for (int off = 32; off >= 1; off >>= 1) {
            const unsigned long long ok = __shfl_xor(mk, off);
            mk = ok < mk ? ok : mk;
        }
        const int rb = r & 1;
        if (lane == 0) rk[rb][wv] = mk;
        __syncthreads();
        const unsigned long long g01 = rk[rb][0] < rk[rb][1] ? rk[rb][0] : rk[rb][1];
        const unsigned long long g23 = rk[rb][2] < rk[rb][3] ? rk[rb][2] : rk[rb][3];
        const unsigned long long gm = g01 < g23 ? g01 : g23;
        if (tid == 0) sel[r] = (int)(unsigned)(gm & 0xffffffffu);
        if (lm == gm) {  // unique owner: remove winner, recompute cached min
#pragma unroll
            for (int i = 0; i < 32; ++i) {
                if (key[i] == gm) key[i] = ~0ULL;
            }
            lm = key[0];
#pragma unroll
            for (int i = 1; i < 32; ++i) lm = key[i] < lm ? key[i] : lm;
        }
        // no trailing barrier: rk double-buffered; sel[r] read only after the
        // post-loop barrier below.
    }
    __syncthreads();

    if (tid < GSZ) {
        const int idx = sel[tid];
        const float* q = base + (size_t)idx * 6;
        const size_t o = ((size_t)row * GSZ + tid) * 3;
        neigh[o + 0] = __fsub_rn(q[0], cx);
        neigh[o + 1] = __fsub_rn(q[1], cy);
        neigh[o + 2] = __fsub_rn(q[2], cz);
        neigh_n[o + 0] = q[3];
        neigh_n[o + 1] = q[4];
        neigh_n[o + 2] = q[5];
    }
}

extern "C" void kernel_launch(void* const* d_in, const int* in_sizes, int n_in,
                              void* d_out, int out_size, void* d_ws, size_t ws_size,
                              hipStream_t stream) {
    const float* xyz = (const float*)d_in[0];
    float* out = (float*)d_out;
    float* neigh   = out;                                   // [8,512,32,3]
    float* neigh_n = out + (size_t)BATCH * NGRP * GSZ * 3;  // [8,512,32,3]
    float* centers = out + (size_t)2 * BATCH * NGRP * GSZ * 3;  // [8,512,3]

    fps_kernel<<<BATCH, 1024, 0, stream>>>(xyz, centers);
    knn_kernel<<<BATCH * NGRP, 256, 0, stream>>>(xyz, centers, neigh, neigh_n);
}

// Round 5
// 937.325 us; speedup vs baseline: 1.3902x; 1.0724x over previous
//
#include <hip/hip_runtime.h>
#include <stdint.h>

#define BATCH 8
#define NPTS 8192
#define NGRP 512
#define GSZ 32

// ((dx*dx + dy*dy) + dz*dz), sequential, round-to-nearest, NO fma contraction —
// matches XLA-CPU strict elementwise square + sequential axis-sum.
__device__ __forceinline__ float sq3(float dx, float dy, float dz) {
    return __fadd_rn(__fadd_rn(__fmul_rn(dx, dx), __fmul_rn(dy, dy)), __fmul_rn(dz, dz));
}

// ---------------------------------------------------------------------------
// FPS: one block per batch, 1024 threads, 8 points/thread in registers.
// Per step (ONE barrier):
//   d[i] = min(d[i], dist2(p_i, B))                      (float, exact)
//   local argmax: linear scan, strict '>', ascending i   (lowest idx on tie)
//   ONE u64 key/thread: (fbits(d)<<13)|(8191-widx)       (exact, unique)
//   6-round key-only wave max reduce
//   unique owner (myk==wk): coords via const-idx cndmask chain -> slot[wv]
//   barrier
//   every thread: 16-key redundant max tree (broadcast ds_reads, unique keys)
//   decode winner wave from key low bits -> one ds_read_b128 of its coords
// Exactness: d>=0 => float bits order-monotonic; max over (8191-idx) ties
// toward LOWEST index == jnp.argmax. Keys globally unique (distinct idx).
// Double-buffered slots => the single barrier is a sufficient hazard fence.
// ---------------------------------------------------------------------------
__global__ __launch_bounds__(1024) void fps_kernel(const float* __restrict__ xyz,
                                                   float* __restrict__ centers) {
    const int b = blockIdx.x;
    const int tid = threadIdx.x;
    const int wv = tid >> 6;  // 0..15

    __shared__ unsigned long long pkey[2][16];
    __shared__ float4 pxyz[2][16];

    float px[8], py[8], pz[8], d[8];
    const float* base = xyz + (size_t)b * NPTS * 6;

#pragma unroll
    for (int i = 0; i < 8; ++i) {
        const int p = i * 1024 + tid;
        const float* q = base + (size_t)p * 6;
        px[i] = q[0]; py[i] = q[1]; pz[i] = q[2];
        d[i] = __int_as_float(0x7f800000);  // +inf: first update = dist-to-point0
    }
    float Bx = base[0], By = base[1], Bz = base[2];
    if (tid == 0) {
        float* c = centers + (size_t)b * NGRP * 3;
        c[0] = Bx; c[1] = By; c[2] = Bz;
    }

    for (int k = 1; k < NGRP; ++k) {
        // ---- fused distance update (float domain only) ----
#pragma unroll
        for (int i = 0; i < 8; ++i) {
            const float nd = sq3(__fsub_rn(px[i], Bx), __fsub_rn(py[i], By), __fsub_rn(pz[i], Bz));
            d[i] = fminf(d[i], nd);
        }
        // ---- local argmax: strict '>' ascending scan => lowest i on ties ----
        float bd = d[0];
        int wi = 0;
#pragma unroll
        for (int i = 1; i < 8; ++i) {
            if (d[i] > bd) { bd = d[i]; wi = i; }
        }
        // ---- single u64 key per thread ----
        const unsigned long long myk =
            ((unsigned long long)__float_as_uint(bd) << 13) |
            (unsigned)(8191 - (wi * 1024 + tid));

        // ---- 6-round key-only wave max reduce (keys unique: no tie logic) ----
        unsigned long long wk = myk;
#pragma unroll
        for (int off = 32; off >= 1; off >>= 1) {
            const unsigned long long ok = __shfl_xor(wk, off);
            wk = ok > wk ? ok : wk;
        }

        const int buf = k & 1;
        // ---- unique per-wave owner writes key + coords ----
        if (myk == wk) {
            float ox = px[0], oy = py[0], oz = pz[0];
#pragma unroll
            for (int i = 1; i < 8; ++i) {  // constant indices only (no scratch)
                const bool c = (wi == i);
                ox = c ? px[i] : ox; oy = c ? py[i] : oy; oz = c ? pz[i] : oz;
            }
            pkey[buf][wv] = myk;
            pxyz[buf][wv] = make_float4(ox, oy, oz, 0.0f);
        }
        __syncthreads();

        // ---- redundant 16-key max tree in every thread (broadcast reads) ----
        unsigned long long g = pkey[buf][0];
#pragma unroll
        for (int w = 1; w < 16; ++w) {
            const unsigned long long t = pkey[buf][w];
            g = t > g ? t : g;
        }
        const int widx = 8191 - (int)((unsigned)g & 8191u);
        const int wwv = (widx & 1023) >> 6;  // winning thread's wave
        const float4 c4 = pxyz[buf][wwv];
        Bx = c4.x; By = c4.y; Bz = c4.z;

        if (tid == 0) {  // fire-and-forget global store, off critical path
            float* c = centers + ((size_t)b * NGRP + k) * 3;
            c[0] = Bx; c[1] = By; c[2] = Bz;
        }
    }
}

// ---------------------------------------------------------------------------
// KNN + gather: one block (256 threads) per (batch, group) row. (unchanged,
// exact: FMA-chain dot matching the reference GEMM; cached local-min rounds)
// ---------------------------------------------------------------------------
__global__ __launch_bounds__(256) void knn_kernel(const float* __restrict__ xyz,
                                                  const float* __restrict__ centers,
                                                  float* __restrict__ neigh,
                                                  float* __restrict__ neigh_n) {
    const int row = blockIdx.x;   // b*NGRP + g
    const int b = row >> 9;
    const int tid = threadIdx.x;
    const int lane = tid & 63;
    const int wv = tid >> 6;  // 0..3

    __shared__ unsigned long long rk[2][4];
    __shared__ int sel[GSZ];

    const float* cptr = centers + (size_t)row * 3;
    const float cx = cptr[0], cy = cptr[1], cz = cptr[2];
    const float c2 = sq3(cx, cy, cz);

    const float* base = xyz + (size_t)b * NPTS * 6;
    unsigned long long key[32];
#pragma unroll
    for (int i = 0; i < 32; ++i) {
        const int p = i * 256 + tid;
        const float* q = base + (size_t)p * 6;
        const float x = q[0], y = q[1], z = q[2];
        const float x2 = sq3(x, y, z);
        // GEMM-style FMA accumulation over k = x,y,z
        const float dot = __fmaf_rn(cz, z, __fmaf_rn(cy, y, __fmul_rn(cx, x)));
        const float d2 = __fadd_rn(__fsub_rn(c2, __fmul_rn(2.0f, dot)), x2);
        // monotonic float->uint transform (handles negative-from-rounding d2)
        unsigned u = __float_as_uint(d2);
        u = (u & 0x80000000u) ? ~u : (u | 0x80000000u);
        key[i] = ((unsigned long long)u << 32) | (unsigned)p;
    }

    // cached local min over this thread's 32 keys
    unsigned long long lm = key[0];
#pragma unroll
    for (int i = 1; i < 32; ++i) lm = key[i] < lm ? key[i] : lm;

    for (int r = 0; r < GSZ; ++r) {
        unsigned long long mk = lm;
#pragma unroll
        for (int off = 32; off >= 1; off >>= 1) {
            const unsigned long long ok = __shfl_xor(mk, off);
            mk = ok < mk ? ok : mk;
        }
        const int rb = r & 1;
        if (lane == 0) rk[rb][wv] = mk;
        __syncthreads();
        const unsigned long long g01 = rk[rb][0] < rk[rb][1] ? rk[rb][0] : rk[rb][1];
        const unsigned long long g23 = rk[rb][2] < rk[rb][3] ? rk[rb][2] : rk[rb][3];
        const unsigned long long gm = g01 < g23 ? g01 : g23;
        if (tid == 0) sel[r] = (int)(unsigned)(gm & 0xffffffffu);
        if (lm == gm) {  // unique owner: remove winner, recompute cached min
#pragma unroll
            for (int i = 0; i < 32; ++i) {
                if (key[i] == gm) key[i] = ~0ULL;
            }
            lm = key[0];
#pragma unroll
            for (int i = 1; i < 32; ++i) lm = key[i] < lm ? key[i] : lm;
        }
    }
    __syncthreads();

    if (tid < GSZ) {
        const int idx = sel[tid];
        const float* q = base + (size_t)idx * 6;
        const size_t o = ((size_t)row * GSZ + tid) * 3;
        neigh[o + 0] = __fsub_rn(q[0], cx);
        neigh[o + 1] = __fsub_rn(q[1], cy);
        neigh[o + 2] = __fsub_rn(q[2], cz);
        neigh_n[o + 0] = q[3];
        neigh_n[o + 1] = q[4];
        neigh_n[o + 2] = q[5];
    }
}

extern "C" void kernel_launch(void* const* d_in, const int* in_sizes, int n_in,
                              void* d_out, int out_size, void* d_ws, size_t ws_size,
                              hipStream_t stream) {
    const float* xyz = (const float*)d_in[0];
    float* out = (float*)d_out;
    float* neigh   = out;                                   // [8,512,32,3]
    float* neigh_n = out + (size_t)BATCH * NGRP * GSZ * 3;  // [8,512,32,3]
    float* centers = out + (size_t)2 * BATCH * NGRP * GSZ * 3;  // [8,512,3]

    fps_kernel<<<BATCH, 1024, 0, stream>>>(xyz, centers);
    knn_kernel<<<BATCH * NGRP, 256, 0, stream>>>(xyz, centers, neigh, neigh_n);
}

// Round 7
// 899.582 us; speedup vs baseline: 1.4485x; 1.0420x over previous
//
#include <hip/hip_runtime.h>
#include <stdint.h>

#define BATCH 8
#define NPTS 8192
#define NGRP 512
#define GSZ 32

typedef float vf2 __attribute__((ext_vector_type(2)));

// ((dx*dx + dy*dy) + dz*dz), sequential, round-to-nearest, NO fma contraction —
// matches XLA-CPU strict elementwise square + sequential axis-sum.
__device__ __forceinline__ float sq3(float dx, float dy, float dz) {
    return __fadd_rn(__fadd_rn(__fmul_rn(dx, dx), __fmul_rn(dy, dy)), __fmul_rn(dz, dz));
}

// ---------------------------------------------------------------------------
// FPS: one block per batch, 1024 threads, 8 points/thread in registers.
// Key trick: key = double(bits = (f32bits(d) << 32) | (8191 - idx)).
// All keys are positive finite doubles -> value order == bit order ==
// (d asc, then (8191-idx) asc). fmax == v_max_f64 (1 instr) gives exact
// argmax-with-lowest-index-tie (== jnp.argmax). Keys globally unique.
// Per step (ONE barrier, NO global memory ops):
//   d[i] = min(d[i], dist2)  [packed-f32, contract(off) => exact RN mul/add]
//   8 key builds + 7 fmax -> local max
//   6 x (shfl_xor + fmax) -> wave max
//   unique per-wave owner (lk==wk): decodes its point from the key low word,
//     writes key + coords to its wave slot
//   barrier (LDS-only drain: no vmcnt stall)
//   all threads: 15-fmax tree over 16 slots -> decode winner wave -> coords
//   tid0 (AFTER the tree => global winner, not per-wave owner): center -> cl
// Centers dumped LDS -> global once at kernel end.
// ---------------------------------------------------------------------------
__global__ __launch_bounds__(1024) void fps_kernel(const float* __restrict__ xyz,
                                                   float* __restrict__ centers) {
    const int b = blockIdx.x;
    const int tid = threadIdx.x;
    const int wv = tid >> 6;  // 0..15

    __shared__ double pkey[2][16];
    __shared__ float4 pxyz[2][16];
    __shared__ float cl[NGRP * 3];  // centers staging (6 KB)

    vf2 px[4], py[4], pz[4], d2[4];
    int lowbits[8];
    const float* base = xyz + (size_t)b * NPTS * 6;

#pragma unroll
    for (int i = 0; i < 8; ++i) {
        const int p = i * 1024 + tid;
        const float* q = base + (size_t)p * 6;
        px[i >> 1][i & 1] = q[0]; py[i >> 1][i & 1] = q[1]; pz[i >> 1][i & 1] = q[2];
        d2[i >> 1][i & 1] = __int_as_float(0x7f800000);  // +inf
        lowbits[i] = 8191 - p;
    }
    float Bx = base[0], By = base[1], Bz = base[2];
    if (tid == 0) { cl[0] = Bx; cl[1] = By; cl[2] = Bz; }

    for (int k = 1; k < NGRP; ++k) {
        // ---- distance update: packed-f32, contraction OFF so the mul/add
        // sequence is bitwise identical to the scalar __f*_rn chain ----
        {
#pragma clang fp contract(off)
            const vf2 bx2 = {Bx, Bx}, by2 = {By, By}, bz2 = {Bz, Bz};
#pragma unroll
            for (int j = 0; j < 4; ++j) {
                const vf2 dx = px[j] - bx2;
                const vf2 dy = py[j] - by2;
                const vf2 dz = pz[j] - bz2;
                const vf2 mx = dx * dx;
                const vf2 my = dy * dy;
                const vf2 mz = dz * dz;
                const vf2 s = (mx + my) + mz;
                d2[j][0] = fminf(d2[j][0], s[0]);
                d2[j][1] = fminf(d2[j][1], s[1]);
            }
        }
        // ---- 8 f64 keys + 7-deep fmax chain (v_max_f64) ----
        double lk = __hiloint2double(__float_as_int(d2[0][0]), lowbits[0]);
#pragma unroll
        for (int i = 1; i < 8; ++i) {
            lk = fmax(lk, __hiloint2double(__float_as_int(d2[i >> 1][i & 1]), lowbits[i]));
        }
        // ---- 6-round key-only wave max (keys unique) ----
        double wk = lk;
#pragma unroll
        for (int off = 32; off >= 1; off >>= 1) {
            wk = fmax(wk, __shfl_xor(wk, off));
        }

        const int buf = k & 1;
        // ---- unique per-wave owner: self-decode point, publish key+coords ----
        if (lk == wk) {
            const int p = 8191 - __double2loint(lk);  // winning global index (mine)
            const int wi = p >> 10;                    // my slot 0..7
            float ox = px[0][0], oy = py[0][0], oz = pz[0][0];
#pragma unroll
            for (int i = 1; i < 8; ++i) {  // constant indices only
                const bool c = (wi == i);
                ox = c ? px[i >> 1][i & 1] : ox;
                oy = c ? py[i >> 1][i & 1] : oy;
                oz = c ? pz[i >> 1][i & 1] : oz;
            }
            pkey[buf][wv] = lk;
            pxyz[buf][wv] = make_float4(ox, oy, oz, 0.0f);
        }
        __syncthreads();  // LDS-only drain (no global ops in flight)

        // ---- redundant 15-fmax tree over 16 slots (broadcast reads) ----
        double g = pkey[buf][0];
#pragma unroll
        for (int w = 1; w < 16; ++w) g = fmax(g, pkey[buf][w]);
        const int widx = 8191 - __double2loint(g);
        const int wwv = (widx & 1023) >> 6;  // winning thread's wave
        const float4 c4 = pxyz[buf][wwv];
        Bx = c4.x; By = c4.y; Bz = c4.z;

        // GLOBAL winner's center -> LDS staging (tid0, after the tree).
        // Read only at kernel end, after a barrier => no extra fence needed.
        if (tid == 0) { cl[k * 3 + 0] = Bx; cl[k * 3 + 1] = By; cl[k * 3 + 2] = Bz; }
    }

    __syncthreads();
    float* cg = centers + (size_t)b * NGRP * 3;
    for (int t = tid; t < NGRP * 3; t += 1024) cg[t] = cl[t];
}

// ---------------------------------------------------------------------------
// KNN + gather: one block (256 threads) per (batch, group) row. (unchanged,
// exact: FMA-chain dot matching the reference GEMM; cached local-min rounds)
// ---------------------------------------------------------------------------
__global__ __launch_bounds__(256) void knn_kernel(const float* __restrict__ xyz,
                                                  const float* __restrict__ centers,
                                                  float* __restrict__ neigh,
                                                  float* __restrict__ neigh_n) {
    const int row = blockIdx.x;   // b*NGRP + g
    const int b = row >> 9;
    const int tid = threadIdx.x;
    const int lane = tid & 63;
    const int wv = tid >> 6;  // 0..3

    __shared__ unsigned long long rk[2][4];
    __shared__ int sel[GSZ];

    const float* cptr = centers + (size_t)row * 3;
    const float cx = cptr[0], cy = cptr[1], cz = cptr[2];
    const float c2 = sq3(cx, cy, cz);

    const float* base = xyz + (size_t)b * NPTS * 6;
    unsigned long long key[32];
#pragma unroll
    for (int i = 0; i < 32; ++i) {
        const int p = i * 256 + tid;
        const float* q = base + (size_t)p * 6;
        const float x = q[0], y = q[1], z = q[2];
        const float x2 = sq3(x, y, z);
        // GEMM-style FMA accumulation over k = x,y,z
        const float dot = __fmaf_rn(cz, z, __fmaf_rn(cy, y, __fmul_rn(cx, x)));
        const float d2 = __fadd_rn(__fsub_rn(c2, __fmul_rn(2.0f, dot)), x2);
        // monotonic float->uint transform (handles negative-from-rounding d2)
        unsigned u = __float_as_uint(d2);
        u = (u & 0x80000000u) ? ~u : (u | 0x80000000u);
        key[i] = ((unsigned long long)u << 32) | (unsigned)p;
    }

    // cached local min over this thread's 32 keys
    unsigned long long lm = key[0];
#pragma unroll
    for (int i = 1; i < 32; ++i) lm = key[i] < lm ? key[i] : lm;

    for (int r = 0; r < GSZ; ++r) {
        unsigned long long mk = lm;
#pragma unroll
        for (int off = 32; off >= 1; off >>= 1) {
            const unsigned long long ok = __shfl_xor(mk, off);
            mk = ok < mk ? ok : mk;
        }
        const int rb = r & 1;
        if (lane == 0) rk[rb][wv] = mk;
        __syncthreads();
        const unsigned long long g01 = rk[rb][0] < rk[rb][1] ? rk[rb][0] : rk[rb][1];
        const unsigned long long g23 = rk[rb][2] < rk[rb][3] ? rk[rb][2] : rk[rb][3];
        const unsigned long long gm = g01 < g23 ? g01 : g23;
        if (tid == 0) sel[r] = (int)(unsigned)(gm & 0xffffffffu);
        if (lm == gm) {  // unique owner: remove winner, recompute cached min
#pragma unroll
            for (int i = 0; i < 32; ++i) {
                if (key[i] == gm) key[i] = ~0ULL;
            }
            lm = key[0];
#pragma unroll
            for (int i = 1; i < 32; ++i) lm = key[i] < lm ? key[i] : lm;
        }
    }
    __syncthreads();

    if (tid < GSZ) {
        const int idx = sel[tid];
        const float* q = base + (size_t)idx * 6;
        const size_t o = ((size_t)row * GSZ + tid) * 3;
        neigh[o + 0] = __fsub_rn(q[0], cx);
        neigh[o + 1] = __fsub_rn(q[1], cy);
        neigh[o + 2] = __fsub_rn(q[2], cz);
        neigh_n[o + 0] = q[3];
        neigh_n[o + 1] = q[4];
        neigh_n[o + 2] = q[5];
    }
}

extern "C" void kernel_launch(void* const* d_in, const int* in_sizes, int n_in,
                              void* d_out, int out_size, void* d_ws, size_t ws_size,
                              hipStream_t stream) {
    const float* xyz = (const float*)d_in[0];
    float* out = (float*)d_out;
    float* neigh   = out;                                   // [8,512,32,3]
    float* neigh_n = out + (size_t)BATCH * NGRP * GSZ * 3;  // [8,512,32,3]
    float* centers = out + (size_t)2 * BATCH * NGRP * GSZ * 3;  // [8,512,3]

    fps_kernel<<<BATCH, 1024, 0, stream>>>(xyz, centers);
    knn_kernel<<<BATCH * NGRP, 256, 0, stream>>>(xyz, centers, neigh, neigh_n);
}

// Round 8
// 821.460 us; speedup vs baseline: 1.5862x; 1.0951x over previous
//
#include <hip/hip_runtime.h>
#include <stdint.h>

#define BATCH 8
#define NPTS 8192
#define NGRP 512
#define GSZ 32

typedef float vf2 __attribute__((ext_vector_type(2)));

// ((dx*dx + dy*dy) + dz*dz), sequential, round-to-nearest, NO fma contraction —
// matches XLA-CPU strict elementwise square + sequential axis-sum.
__device__ __forceinline__ float sq3(float dx, float dy, float dz) {
    return __fadd_rn(__fadd_rn(__fmul_rn(dx, dx), __fmul_rn(dy, dy)), __fmul_rn(dz, dz));
}

// ---------------------------------------------------------------------------
// FPS: one block per batch, 512 threads, 16 points/thread in registers.
// All point coords ALSO staged once in LDS as float4 P4[8192] (128 KB) so the
// winner's coords are a single broadcast ds_read_b128 by index — no owner
// reconstruct, no coord-carrying reduces.
// Per step (ONE barrier, NO global ops):
//   d[i] = min(d[i], dist2)   [packed f32, contract(off) => exact RN mul/add]
//   f32 pairwise tree (15 merges, depth 4, prefer lower slot on ties)
//     -> thread-local (max d, lowest idx)   [exact: idx ascending in slot]
//   ONE f64 key: hi=f32bits(d), lo=8191-idx  (positive doubles: bit order ==
//     value order == (d asc, then lowest-idx-wins); keys unique)
//   6 x (shfl_xor + v_max_f64) wave reduce; lane0 -> pkey[buf][wv]
//   barrier
//   7-fmax tree over 8 slots -> widx -> float4 c4 = P4[widx]
//   tid0 stages center coords into LDS cl[]
// Centers dumped LDS -> global once at kernel end.
// ---------------------------------------------------------------------------
__global__ __launch_bounds__(512) void fps_kernel(const float* __restrict__ xyz,
                                                  float* __restrict__ centers) {
    const int b = blockIdx.x;
    const int tid = threadIdx.x;
    const int lane = tid & 63;
    const int wv = tid >> 6;  // 0..7

    __shared__ float4 P4[NPTS];      // 128 KB coord table
    __shared__ double pkey[2][8];
    __shared__ float cl[NGRP * 3];   // 6 KB centers staging

    vf2 px[8], py[8], pz[8], d2[8];
    const float* base = xyz + (size_t)b * NPTS * 6;

#pragma unroll
    for (int i = 0; i < 16; ++i) {
        const int p = i * 512 + tid;
        const float* q = base + (size_t)p * 6;
        const float x = q[0], y = q[1], z = q[2];
        px[i >> 1][i & 1] = x; py[i >> 1][i & 1] = y; pz[i >> 1][i & 1] = z;
        d2[i >> 1][i & 1] = __int_as_float(0x7f800000);  // +inf
        P4[p] = make_float4(x, y, z, 0.0f);
    }
    float Bx = base[0], By = base[1], Bz = base[2];
    if (tid == 0) { cl[0] = Bx; cl[1] = By; cl[2] = Bz; }
    __syncthreads();  // P4 ready

    for (int k = 1; k < NGRP; ++k) {
        // ---- distance update: packed f32, contraction OFF (exact RN chain) ----
        {
#pragma clang fp contract(off)
            const vf2 bx2 = {Bx, Bx}, by2 = {By, By}, bz2 = {Bz, Bz};
#pragma unroll
            for (int j = 0; j < 8; ++j) {
                const vf2 dx = px[j] - bx2;
                const vf2 dy = py[j] - by2;
                const vf2 dz = pz[j] - bz2;
                const vf2 mx = dx * dx;
                const vf2 my = dy * dy;
                const vf2 mz = dz * dz;
                const vf2 s = (mx + my) + mz;
                d2[j][0] = fminf(d2[j][0], s[0]);
                d2[j][1] = fminf(d2[j][1], s[1]);
            }
        }
        // ---- f32 pairwise argmax tree, prefer lower slot (= lower idx) ----
        float md[8];
        int mi[8];
#pragma unroll
        for (int j = 0; j < 8; ++j) {
            const bool c = d2[j][1] > d2[j][0];  // strict: keep [0] on tie
            md[j] = c ? d2[j][1] : d2[j][0];
            mi[j] = c ? (2 * j + 1) : (2 * j);
        }
#pragma unroll
        for (int s = 4; s >= 1; s >>= 1) {
#pragma unroll
            for (int j = 0; j < s; ++j) {
                const bool c = md[j + s] > md[j];  // strict: keep lower group on tie
                md[j] = c ? md[j + s] : md[j];
                mi[j] = c ? mi[j + s] : mi[j];
            }
        }
        // ---- single f64 key: (d bits, 8191-idx); positive, unique, monotonic ----
        const double lk =
            __hiloint2double(__float_as_int(md[0]), 8191 - (mi[0] * 512 + tid));
        double wk = lk;
#pragma unroll
        for (int off = 32; off >= 1; off >>= 1) {
            wk = fmax(wk, __shfl_xor(wk, off));
        }

        const int buf = k & 1;
        if (lane == 0) pkey[buf][wv] = wk;
        __syncthreads();  // LDS-only drain

        // ---- 7-fmax tree over 8 wave slots (broadcast reads) ----
        double g = pkey[buf][0];
#pragma unroll
        for (int w = 1; w < 8; ++w) g = fmax(g, pkey[buf][w]);
        const int widx = 8191 - __double2loint(g);
        const float4 c4 = P4[widx];  // broadcast ds_read_b128
        Bx = c4.x; By = c4.y; Bz = c4.z;

        if (tid == 0) { cl[k * 3 + 0] = Bx; cl[k * 3 + 1] = By; cl[k * 3 + 2] = Bz; }
    }

    __syncthreads();
    float* cg = centers + (size_t)b * NGRP * 3;
    for (int t = tid; t < NGRP * 3; t += 512) cg[t] = cl[t];
}

// ---------------------------------------------------------------------------
// KNN + gather: one block (256 threads) per (batch, group) row. (unchanged,
// exact: FMA-chain dot matching the reference GEMM; cached local-min rounds)
// ---------------------------------------------------------------------------
__global__ __launch_bounds__(256) void knn_kernel(const float* __restrict__ xyz,
                                                  const float* __restrict__ centers,
                                                  float* __restrict__ neigh,
                                                  float* __restrict__ neigh_n) {
    const int row = blockIdx.x;   // b*NGRP + g
    const int b = row >> 9;
    const int tid = threadIdx.x;
    const int lane = tid & 63;
    const int wv = tid >> 6;  // 0..3

    __shared__ unsigned long long rk[2][4];
    __shared__ int sel[GSZ];

    const float* cptr = centers + (size_t)row * 3;
    const float cx = cptr[0], cy = cptr[1], cz = cptr[2];
    const float c2 = sq3(cx, cy, cz);

    const float* base = xyz + (size_t)b * NPTS * 6;
    unsigned long long key[32];
#pragma unroll
    for (int i = 0; i < 32; ++i) {
        const int p = i * 256 + tid;
        const float* q = base + (size_t)p * 6;
        const float x = q[0], y = q[1], z = q[2];
        const float x2 = sq3(x, y, z);
        // GEMM-style FMA accumulation over k = x,y,z
        const float dot = __fmaf_rn(cz, z, __fmaf_rn(cy, y, __fmul_rn(cx, x)));
        const float d2 = __fadd_rn(__fsub_rn(c2, __fmul_rn(2.0f, dot)), x2);
        // monotonic float->uint transform (handles negative-from-rounding d2)
        unsigned u = __float_as_uint(d2);
        u = (u & 0x80000000u) ? ~u : (u | 0x80000000u);
        key[i] = ((unsigned long long)u << 32) | (unsigned)p;
    }

    // cached local min over this thread's 32 keys
    unsigned long long lm = key[0];
#pragma unroll
    for (int i = 1; i < 32; ++i) lm = key[i] < lm ? key[i] : lm;

    for (int r = 0; r < GSZ; ++r) {
        unsigned long long mk = lm;
#pragma unroll
        for (int off = 32; off >= 1; off >>= 1) {
            const unsigned long long ok = __shfl_xor(mk, off);
            mk = ok < mk ? ok : mk;
        }
        const int rb = r & 1;
        if (lane == 0) rk[rb][wv] = mk;
        __syncthreads();
        const unsigned long long g01 = rk[rb][0] < rk[rb][1] ? rk[rb][0] : rk[rb][1];
        const unsigned long long g23 = rk[rb][2] < rk[rb][3] ? rk[rb][2] : rk[rb][3];
        const unsigned long long gm = g01 < g23 ? g01 : g23;
        if (tid == 0) sel[r] = (int)(unsigned)(gm & 0xffffffffu);
        if (lm == gm) {  // unique owner: remove winner, recompute cached min
#pragma unroll
            for (int i = 0; i < 32; ++i) {
                if (key[i] == gm) key[i] = ~0ULL;
            }
            lm = key[0];
#pragma unroll
            for (int i = 1; i < 32; ++i) lm = key[i] < lm ? key[i] : lm;
        }
    }
    __syncthreads();

    if (tid < GSZ) {
        const int idx = sel[tid];
        const float* q = base + (size_t)idx * 6;
        const size_t o = ((size_t)row * GSZ + tid) * 3;
        neigh[o + 0] = __fsub_rn(q[0], cx);
        neigh[o + 1] = __fsub_rn(q[1], cy);
        neigh[o + 2] = __fsub_rn(q[2], cz);
        neigh_n[o + 0] = q[3];
        neigh_n[o + 1] = q[4];
        neigh_n[o + 2] = q[5];
    }
}

extern "C" void kernel_launch(void* const* d_in, const int* in_sizes, int n_in,
                              void* d_out, int out_size, void* d_ws, size_t ws_size,
                              hipStream_t stream) {
    const float* xyz = (const float*)d_in[0];
    float* out = (float*)d_out;
    float* neigh   = out;                                   // [8,512,32,3]
    float* neigh_n = out + (size_t)BATCH * NGRP * GSZ * 3;  // [8,512,32,3]
    float* centers = out + (size_t)2 * BATCH * NGRP * GSZ * 3;  // [8,512,3]

    fps_kernel<<<BATCH, 512, 0, stream>>>(xyz, centers);
    knn_kernel<<<BATCH * NGRP, 256, 0, stream>>>(xyz, centers, neigh, neigh_n);
}

// Round 9
// 667.635 us; speedup vs baseline: 1.9517x; 1.2304x over previous
//
#include <hip/hip_runtime.h>
#include <stdint.h>

#define BATCH 8
#define NPTS 8192
#define NGRP 512
#define GSZ 32

typedef float vf2 __attribute__((ext_vector_type(2)));

// ((dx*dx + dy*dy) + dz*dz), sequential, round-to-nearest, NO fma contraction —
// matches XLA-CPU strict elementwise square + sequential axis-sum.
__device__ __forceinline__ float sq3(float dx, float dy, float dz) {
    return __fadd_rn(__fadd_rn(__fmul_rn(dx, dx), __fmul_rn(dy, dy)), __fmul_rn(dz, dz));
}

// ---------------------------------------------------------------------------
// FPS: one block per batch, 512 threads, 16 points/thread in registers.
// Coords staged once into LDS float4 P4[8192] (128 KB): winner fetch is one
// broadcast ds_read_b128 by index — no owner reconstruct, no coord carries.
// Per step (ONE barrier, NO global ops):
//   d2 = pk_min(d2, pk-dist2)          [VOP3P, contract(off) => exact RN]
//   packed max tree (7 pk_max + 1 fmax) -> mx  (no index carry)
//   lowest-index recovery: descending equality scan over the 16 slots
//     (mx is bit-equal to a d2 element; lower slot == lower global idx)
//   ONE f64 key: hi=f32bits(mx), lo=8191-idx  (positive doubles: bit order ==
//     value order == (d asc, lowest-idx tiebreak); keys globally unique)
//   6 x (shfl_xor + v_max_f64) wave reduce; lane0 -> pkey[buf][wv]
//   barrier
//   7-fmax tree over 8 slots -> widx -> float4 c4 = P4[widx]
//   tid0 stages center into LDS cl[]
// Centers dumped LDS -> global once at kernel end.
// ---------------------------------------------------------------------------
__global__ __launch_bounds__(512) void fps_kernel(const float* __restrict__ xyz,
                                                  float* __restrict__ centers) {
    const int b = blockIdx.x;
    const int tid = threadIdx.x;
    const int lane = tid & 63;
    const int wv = tid >> 6;  // 0..7

    __shared__ float4 P4[NPTS];      // 128 KB coord table
    __shared__ double pkey[2][8];
    __shared__ float cl[NGRP * 3];   // 6 KB centers staging

    vf2 px[8], py[8], pz[8], d2[8];
    const float* base = xyz + (size_t)b * NPTS * 6;

#pragma unroll
    for (int i = 0; i < 16; ++i) {
        const int p = i * 512 + tid;
        const float* q = base + (size_t)p * 6;
        const float x = q[0], y = q[1], z = q[2];
        px[i >> 1][i & 1] = x; py[i >> 1][i & 1] = y; pz[i >> 1][i & 1] = z;
        d2[i >> 1][i & 1] = __int_as_float(0x7f800000);  // +inf
        P4[p] = make_float4(x, y, z, 0.0f);
    }
    float Bx = base[0], By = base[1], Bz = base[2];
    if (tid == 0) { cl[0] = Bx; cl[1] = By; cl[2] = Bz; }
    __syncthreads();  // P4 ready

    for (int k = 1; k < NGRP; ++k) {
        // ---- packed distance update, contraction OFF (exact RN mul/add) ----
        {
#pragma clang fp contract(off)
            const vf2 bx2 = {Bx, Bx}, by2 = {By, By}, bz2 = {Bz, Bz};
#pragma unroll
            for (int j = 0; j < 8; ++j) {
                const vf2 dx = px[j] - bx2;
                const vf2 dy = py[j] - by2;
                const vf2 dz = pz[j] - bz2;
                const vf2 mx2 = dx * dx;
                const vf2 my2 = dy * dy;
                const vf2 mz2 = dz * dz;
                const vf2 s = (mx2 + my2) + mz2;
                d2[j] = __builtin_elementwise_min(d2[j], s);  // v_pk_min_f32
            }
        }
        // ---- packed max tree (values only) ----
        vf2 mv = d2[0];
#pragma unroll
        for (int j = 1; j < 8; ++j) mv = __builtin_elementwise_max(mv, d2[j]);
        const float mx = fmaxf(mv[0], mv[1]);
        // ---- lowest-index recovery: descending equality scan ----
        int wi = 0;
#pragma unroll
        for (int i = 15; i >= 1; --i) {
            wi = (d2[i >> 1][i & 1] == mx) ? i : wi;  // ends at LOWEST matching slot
        }
        // ---- single f64 key: (d bits, 8191-idx); positive, unique, monotonic ----
        const double lk =
            __hiloint2double(__float_as_int(mx), 8191 - (wi * 512 + tid));
        double wk = lk;
#pragma unroll
        for (int off = 32; off >= 1; off >>= 1) {
            wk = fmax(wk, __shfl_xor(wk, off));
        }

        const int buf = k & 1;
        if (lane == 0) pkey[buf][wv] = wk;
        __syncthreads();  // LDS-only drain

        // ---- 7-fmax tree over 8 wave slots (broadcast reads) ----
        double g = pkey[buf][0];
#pragma unroll
        for (int w = 1; w < 8; ++w) g = fmax(g, pkey[buf][w]);
        const int widx = 8191 - __double2loint(g);
        const float4 c4 = P4[widx];  // broadcast ds_read_b128
        Bx = c4.x; By = c4.y; Bz = c4.z;

        if (tid == 0) { cl[k * 3 + 0] = Bx; cl[k * 3 + 1] = By; cl[k * 3 + 2] = Bz; }
    }

    __syncthreads();
    float* cg = centers + (size_t)b * NGRP * 3;
    for (int t = tid; t < NGRP * 3; t += 512) cg[t] = cl[t];
}

// ---------------------------------------------------------------------------
// KNN + gather: one block (256 threads) per (batch, group) row. (unchanged,
// exact: FMA-chain dot matching the reference GEMM; cached local-min rounds)
// ---------------------------------------------------------------------------
__global__ __launch_bounds__(256) void knn_kernel(const float* __restrict__ xyz,
                                                  const float* __restrict__ centers,
                                                  float* __restrict__ neigh,
                                                  float* __restrict__ neigh_n) {
    const int row = blockIdx.x;   // b*NGRP + g
    const int b = row >> 9;
    const int tid = threadIdx.x;
    const int lane = tid & 63;
    const int wv = tid >> 6;  // 0..3

    __shared__ unsigned long long rk[2][4];
    __shared__ int sel[GSZ];

    const float* cptr = centers + (size_t)row * 3;
    const float cx = cptr[0], cy = cptr[1], cz = cptr[2];
    const float c2 = sq3(cx, cy, cz);

    const float* base = xyz + (size_t)b * NPTS * 6;
    unsigned long long key[32];
#pragma unroll
    for (int i = 0; i < 32; ++i) {
        const int p = i * 256 + tid;
        const float* q = base + (size_t)p * 6;
        const float x = q[0], y = q[1], z = q[2];
        const float x2 = sq3(x, y, z);
        // GEMM-style FMA accumulation over k = x,y,z
        const float dot = __fmaf_rn(cz, z, __fmaf_rn(cy, y, __fmul_rn(cx, x)));
        const float d2 = __fadd_rn(__fsub_rn(c2, __fmul_rn(2.0f, dot)), x2);
        // monotonic float->uint transform (handles negative-from-rounding d2)
        unsigned u = __float_as_uint(d2);
        u = (u & 0x80000000u) ? ~u : (u | 0x80000000u);
        key[i] = ((unsigned long long)u << 32) | (unsigned)p;
    }

    // cached local min over this thread's 32 keys
    unsigned long long lm = key[0];
#pragma unroll
    for (int i = 1; i < 32; ++i) lm = key[i] < lm ? key[i] : lm;

    for (int r = 0; r < GSZ; ++r) {
        unsigned long long mk = lm;
#pragma unroll
        for (int off = 32; off >= 1; off >>= 1) {
            const unsigned long long ok = __shfl_xor(mk, off);
            mk = ok < mk ? ok : mk;
        }
        const int rb = r & 1;
        if (lane == 0) rk[rb][wv] = mk;
        __syncthreads();
        const unsigned long long g01 = rk[rb][0] < rk[rb][1] ? rk[rb][0] : rk[rb][1];
        const unsigned long long g23 = rk[rb][2] < rk[rb][3] ? rk[rb][2] : rk[rb][3];
        const unsigned long long gm = g01 < g23 ? g01 : g23;
        if (tid == 0) sel[r] = (int)(unsigned)(gm & 0xffffffffu);
        if (lm == gm) {  // unique owner: remove winner, recompute cached min
#pragma unroll
            for (int i = 0; i < 32; ++i) {
                if (key[i] == gm) key[i] = ~0ULL;
            }
            lm = key[0];
#pragma unroll
            for (int i = 1; i < 32; ++i) lm = key[i] < lm ? key[i] : lm;
        }
    }
    __syncthreads();

    if (tid < GSZ) {
        const int idx = sel[tid];
        const float* q = base + (size_t)idx * 6;
        const size_t o = ((size_t)row * GSZ + tid) * 3;
        neigh[o + 0] = __fsub_rn(q[0], cx);
        neigh[o + 1] = __fsub_rn(q[1], cy);
        neigh[o + 2] = __fsub_rn(q[2], cz);
        neigh_n[o + 0] = q[3];
        neigh_n[o + 1] = q[4];
        neigh_n[o + 2] = q[5];
    }
}

extern "C" void kernel_launch(void* const* d_in, const int* in_sizes, int n_in,
                              void* d_out, int out_size, void* d_ws, size_t ws_size,
                              hipStream_t stream) {
    const float* xyz = (const float*)d_in[0];
    float* out = (float*)d_out;
    float* neigh   = out;                                   // [8,512,32,3]
    float* neigh_n = out + (size_t)BATCH * NGRP * GSZ * 3;  // [8,512,32,3]
    float* centers = out + (size_t)2 * BATCH * NGRP * GSZ * 3;  // [8,512,3]

    fps_kernel<<<BATCH, 512, 0, stream>>>(xyz, centers);
    knn_kernel<<<BATCH * NGRP, 256, 0, stream>>>(xyz, centers, neigh, neigh_n);
}

// Round 10
// 629.253 us; speedup vs baseline: 2.0707x; 1.0610x over previous
//
#include <hip/hip_runtime.h>
#include <stdint.h>

#define BATCH 8
#define NPTS 8192
#define NGRP 512
#define GSZ 32

typedef float vf2 __attribute__((ext_vector_type(2)));

// ((dx*dx + dy*dy) + dz*dz), sequential, round-to-nearest, NO fma contraction —
// matches XLA-CPU strict elementwise square + sequential axis-sum.
__device__ __forceinline__ float sq3(float dx, float dy, float dz) {
    return __fadd_rn(__fadd_rn(__fmul_rn(dx, dx), __fmul_rn(dy, dy)), __fmul_rn(dz, dz));
}

// ---- DPP wave-64 reduction steps (VALU pipe, no DS ops) ----
// update_dpp(old=v, src=v): invalid source lanes yield v (identity for max/min).
template <int C>
__device__ __forceinline__ float dpp_max_f32_step(float v) {
    const int t = __builtin_amdgcn_update_dpp(__float_as_int(v), __float_as_int(v),
                                              C, 0xF, 0xF, false);
    return fmaxf(v, __int_as_float(t));
}
template <int C>
__device__ __forceinline__ unsigned dpp_min_u32_step(unsigned v) {
    const unsigned t = (unsigned)__builtin_amdgcn_update_dpp((int)v, (int)v,
                                                             C, 0xF, 0xF, false);
    return v < t ? v : t;
}
// Full-wave max of non-negative f32; result uniform via readlane(63).
__device__ __forceinline__ float wave_max_f32(float v) {
    v = dpp_max_f32_step<0x111>(v);  // row_shr:1
    v = dpp_max_f32_step<0x112>(v);  // row_shr:2
    v = dpp_max_f32_step<0x114>(v);  // row_shr:4
    v = dpp_max_f32_step<0x118>(v);  // row_shr:8
    v = dpp_max_f32_step<0x142>(v);  // row_bcast:15
    v = dpp_max_f32_step<0x143>(v);  // row_bcast:31
    return __int_as_float(__builtin_amdgcn_readlane(__float_as_int(v), 63));
}
__device__ __forceinline__ unsigned wave_min_u32(unsigned v) {
    v = dpp_min_u32_step<0x111>(v);
    v = dpp_min_u32_step<0x112>(v);
    v = dpp_min_u32_step<0x114>(v);
    v = dpp_min_u32_step<0x118>(v);
    v = dpp_min_u32_step<0x142>(v);
    v = dpp_min_u32_step<0x143>(v);
    return (unsigned)__builtin_amdgcn_readlane((int)v, 63);
}

// ---------------------------------------------------------------------------
// FPS: one block per batch, 512 threads, 16 points/thread in registers.
// Coords staged once into LDS float4 P4[8192] (128 KB): winner fetch is one
// broadcast ds_read_b128 by index.
// Per step (ONE barrier, NO global ops, NO DS-pipe reduces):
//   d2 = pk_min(d2, pk-dist2)          [VOP3P, contract(off) => exact RN]
//   packed max tree -> mx; DPP v_max_f32 chain -> wmx (uniform)
//   lowest-slot eq-scan -> wi; cand = (mx==wmx) ? wi*512+tid : ~0u
//   DPP v_min_u32 chain -> widx_w  (== wave argmax, lowest idx on ties)
//   lane0: f64 key (hi=f32bits(wmx), lo=8191-widx_w) -> pkey[buf][wv]
//   barrier; 7-fmax tree over 8 slots -> widx -> P4[widx]; tid0 -> cl[]
// Exact: update arithmetic byte-identical to reference chain; argmax exact
// (ties resolved to lowest index at every level, == jnp.argmax).
// ---------------------------------------------------------------------------
__global__ __launch_bounds__(512) void fps_kernel(const float* __restrict__ xyz,
                                                  float* __restrict__ centers) {
    const int b = blockIdx.x;
    const int tid = threadIdx.x;
    const int lane = tid & 63;
    const int wv = tid >> 6;  // 0..7

    __shared__ float4 P4[NPTS];      // 128 KB coord table
    __shared__ double pkey[2][8];
    __shared__ float cl[NGRP * 3];   // 6 KB centers staging

    vf2 px[8], py[8], pz[8], d2[8];
    const float* base = xyz + (size_t)b * NPTS * 6;

#pragma unroll
    for (int i = 0; i < 16; ++i) {
        const int p = i * 512 + tid;
        const float* q = base + (size_t)p * 6;
        const float x = q[0], y = q[1], z = q[2];
        px[i >> 1][i & 1] = x; py[i >> 1][i & 1] = y; pz[i >> 1][i & 1] = z;
        d2[i >> 1][i & 1] = __int_as_float(0x7f800000);  // +inf
        P4[p] = make_float4(x, y, z, 0.0f);
    }
    float Bx = base[0], By = base[1], Bz = base[2];
    if (tid == 0) { cl[0] = Bx; cl[1] = By; cl[2] = Bz; }
    __syncthreads();  // P4 ready

    for (int k = 1; k < NGRP; ++k) {
        // ---- packed distance update, contraction OFF (exact RN mul/add) ----
        {
#pragma clang fp contract(off)
            const vf2 bx2 = {Bx, Bx}, by2 = {By, By}, bz2 = {Bz, Bz};
#pragma unroll
            for (int j = 0; j < 8; ++j) {
                const vf2 dx = px[j] - bx2;
                const vf2 dy = py[j] - by2;
                const vf2 dz = pz[j] - bz2;
                const vf2 mx2 = dx * dx;
                const vf2 my2 = dy * dy;
                const vf2 mz2 = dz * dz;
                const vf2 s = (mx2 + my2) + mz2;
                d2[j] = __builtin_elementwise_min(d2[j], s);  // v_pk_min_f32
            }
        }
        // ---- packed max tree (values only) ----
        vf2 mv = d2[0];
#pragma unroll
        for (int j = 1; j < 8; ++j) mv = __builtin_elementwise_max(mv, d2[j]);
        const float mx = fmaxf(mv[0], mv[1]);
        // ---- DPP wave max (uniform) ----
        const float wmx = wave_max_f32(mx);
        // ---- lowest-slot recovery + candidate index ----
        int wi = 0;
#pragma unroll
        for (int i = 15; i >= 1; --i) {
            wi = (d2[i >> 1][i & 1] == mx) ? i : wi;  // lowest matching slot
        }
        const unsigned cand = (mx == wmx) ? (unsigned)(wi * 512 + tid) : 0xFFFFFFFFu;
        // ---- DPP wave min over candidates -> wave's winning index ----
        const unsigned widx_w = wave_min_u32(cand);

        const int buf = k & 1;
        if (lane == 0) {
            pkey[buf][wv] =
                __hiloint2double(__float_as_int(wmx), 8191 - (int)widx_w);
        }
        __syncthreads();  // LDS-only drain

        // ---- 7-fmax tree over 8 wave slots (broadcast reads) ----
        double g = pkey[buf][0];
#pragma unroll
        for (int w = 1; w < 8; ++w) g = fmax(g, pkey[buf][w]);
        const int widx = 8191 - __double2loint(g);
        const float4 c4 = P4[widx];  // broadcast ds_read_b128
        Bx = c4.x; By = c4.y; Bz = c4.z;

        if (tid == 0) { cl[k * 3 + 0] = Bx; cl[k * 3 + 1] = By; cl[k * 3 + 2] = Bz; }
    }

    __syncthreads();
    float* cg = centers + (size_t)b * NGRP * 3;
    for (int t = tid; t < NGRP * 3; t += 512) cg[t] = cl[t];
}

// ---------------------------------------------------------------------------
// KNN + gather: one block (256 threads) per (batch, group) row.
// FP math byte-identical to the passing version. Per selection round the u64
// wave min is two DPP chains: umin over transformed dist bits, then umin over
// index among dist-equal owners (lexicographic u64 min, bit-exact).
// ---------------------------------------------------------------------------
__global__ __launch_bounds__(256) void knn_kernel(const float* __restrict__ xyz,
                                                  const float* __restrict__ centers,
                                                  float* __restrict__ neigh,
                                                  float* __restrict__ neigh_n) {
    const int row = blockIdx.x;   // b*NGRP + g
    const int b = row >> 9;
    const int tid = threadIdx.x;
    const int lane = tid & 63;
    const int wv = tid >> 6;  // 0..3

    __shared__ unsigned long long rk[2][4];
    __shared__ int sel[GSZ];

    const float* cptr = centers + (size_t)row * 3;
    const float cx = cptr[0], cy = cptr[1], cz = cptr[2];
    const float c2 = sq3(cx, cy, cz);

    const float* base = xyz + (size_t)b * NPTS * 6;
    unsigned long long key[32];
#pragma unroll
    for (int i = 0; i < 32; ++i) {
        const int p = i * 256 + tid;
        const float* q = base + (size_t)p * 6;
        const float x = q[0], y = q[1], z = q[2];
        const float x2 = sq3(x, y, z);
        // GEMM-style FMA accumulation over k = x,y,z
        const float dot = __fmaf_rn(cz, z, __fmaf_rn(cy, y, __fmul_rn(cx, x)));
        const float d2 = __fadd_rn(__fsub_rn(c2, __fmul_rn(2.0f, dot)), x2);
        // monotonic float->uint transform (handles negative-from-rounding d2)
        unsigned u = __float_as_uint(d2);
        u = (u & 0x80000000u) ? ~u : (u | 0x80000000u);
        key[i] = ((unsigned long long)u << 32) | (unsigned)p;
    }

    // cached local min over this thread's 32 keys
    unsigned long long lm = key[0];
#pragma unroll
    for (int i = 1; i < 32; ++i) lm = key[i] < lm ? key[i] : lm;

    for (int r = 0; r < GSZ; ++r) {
        // ---- wave u64 min via two DPP u32 chains ----
        const unsigned hi = (unsigned)(lm >> 32);
        const unsigned minhi = wave_min_u32(hi);
        const unsigned cand = (hi == minhi) ? (unsigned)lm : 0xFFFFFFFFu;
        const unsigned minlo = wave_min_u32(cand);
        const unsigned long long mk = ((unsigned long long)minhi << 32) | minlo;

        const int rb = r & 1;
        if (lane == 0) rk[rb][wv] = mk;
        __syncthreads();
        const unsigned long long g01 = rk[rb][0] < rk[rb][1] ? rk[rb][0] : rk[rb][1];
        const unsigned long long g23 = rk[rb][2] < rk[rb][3] ? rk[rb][2] : rk[rb][3];
        const unsigned long long gm = g01 < g23 ? g01 : g23;
        if (tid == 0) sel[r] = (int)(unsigned)(gm & 0xffffffffu);
        if (lm == gm) {  // unique owner: remove winner, recompute cached min
#pragma unroll
            for (int i = 0; i < 32; ++i) {
                if (key[i] == gm) key[i] = ~0ULL;
            }
            lm = key[0];
#pragma unroll
            for (int i = 1; i < 32; ++i) lm = key[i] < lm ? key[i] : lm;
        }
    }
    __syncthreads();

    if (tid < GSZ) {
        const int idx = sel[tid];
        const float* q = base + (size_t)idx * 6;
        const size_t o = ((size_t)row * GSZ + tid) * 3;
        neigh[o + 0] = __fsub_rn(q[0], cx);
        neigh[o + 1] = __fsub_rn(q[1], cy);
        neigh[o + 2] = __fsub_rn(q[2], cz);
        neigh_n[o + 0] = q[3];
        neigh_n[o + 1] = q[4];
        neigh_n[o + 2] = q[5];
    }
}

extern "C" void kernel_launch(void* const* d_in, const int* in_sizes, int n_in,
                              void* d_out, int out_size, void* d_ws, size_t ws_size,
                              hipStream_t stream) {
    const float* xyz = (const float*)d_in[0];
    float* out = (float*)d_out;
    float* neigh   = out;                                   // [8,512,32,3]
    float* neigh_n = out + (size_t)BATCH * NGRP * GSZ * 3;  // [8,512,32,3]
    float* centers = out + (size_t)2 * BATCH * NGRP * GSZ * 3;  // [8,512,3]

    fps_kernel<<<BATCH, 512, 0, stream>>>(xyz, centers);
    knn_kernel<<<BATCH * NGRP, 256, 0, stream>>>(xyz, centers, neigh, neigh_n);
}

// Round 11
// 511.897 us; speedup vs baseline: 2.5455x; 1.2293x over previous
//
#include <hip/hip_runtime.h>
#include <stdint.h>

#define BATCH 8
#define NPTS 8192
#define NGRP 512
#define GSZ 32

typedef float vf2 __attribute__((ext_vector_type(2)));

// ((dx*dx + dy*dy) + dz*dz), sequential, round-to-nearest, NO fma contraction —
// matches XLA-CPU strict elementwise square + sequential axis-sum.
__device__ __forceinline__ float sq3(float dx, float dy, float dz) {
    return __fadd_rn(__fadd_rn(__fmul_rn(dx, dx), __fmul_rn(dy, dy)), __fmul_rn(dz, dz));
}

// ---- DPP wave-64 reduction steps (VALU pipe, no DS ops) ----
template <int C>
__device__ __forceinline__ float dpp_max_f32_step(float v) {
    const int t = __builtin_amdgcn_update_dpp(__float_as_int(v), __float_as_int(v),
                                              C, 0xF, 0xF, false);
    return fmaxf(v, __int_as_float(t));
}
template <int C>
__device__ __forceinline__ unsigned dpp_min_u32_step(unsigned v) {
    const unsigned t = (unsigned)__builtin_amdgcn_update_dpp((int)v, (int)v,
                                                             C, 0xF, 0xF, false);
    return v < t ? v : t;
}
__device__ __forceinline__ float wave_max_f32(float v) {
    v = dpp_max_f32_step<0x111>(v);
    v = dpp_max_f32_step<0x112>(v);
    v = dpp_max_f32_step<0x114>(v);
    v = dpp_max_f32_step<0x118>(v);
    v = dpp_max_f32_step<0x142>(v);
    v = dpp_max_f32_step<0x143>(v);
    return __int_as_float(__builtin_amdgcn_readlane(__float_as_int(v), 63));
}
__device__ __forceinline__ unsigned wave_min_u32(unsigned v) {
    v = dpp_min_u32_step<0x111>(v);
    v = dpp_min_u32_step<0x112>(v);
    v = dpp_min_u32_step<0x114>(v);
    v = dpp_min_u32_step<0x118>(v);
    v = dpp_min_u32_step<0x142>(v);
    v = dpp_min_u32_step<0x143>(v);
    return (unsigned)__builtin_amdgcn_readlane((int)v, 63);
}

// ---------------------------------------------------------------------------
// FPS: one block per batch, 512 threads, 16 points/thread in registers.
// Same structure as the passing R10 kernel; this round: float4 init loads,
// ballot shortcut for the index reduce (unique-winner fast path), double2
// pkey reads. Exact: FP arithmetic byte-identical; argmax exact with
// lowest-index ties at every level (== jnp.argmax).
// ---------------------------------------------------------------------------
__global__ __launch_bounds__(512) void fps_kernel(const float* __restrict__ xyz,
                                                  float* __restrict__ centers) {
    const int b = blockIdx.x;
    const int tid = threadIdx.x;
    const int wv = tid >> 6;  // 0..7

    __shared__ float4 P4[NPTS];      // 128 KB coord table
    __shared__ double pkey[2][8];
    __shared__ float cl[NGRP * 3];   // 6 KB centers staging

    vf2 px[8], py[8], pz[8], d2[8];
    const float* base = xyz + (size_t)b * NPTS * 6;

#pragma unroll
    for (int i = 0; i < 16; ++i) {
        const int p = i * 512 + tid;
        // one dwordx4 @ p*24 (dword-aligned; covers x,y,z,+nx) instead of 3 dwords
        const float4 v4 = *reinterpret_cast<const float4*>(base + (size_t)p * 6);
        px[i >> 1][i & 1] = v4.x; py[i >> 1][i & 1] = v4.y; pz[i >> 1][i & 1] = v4.z;
        d2[i >> 1][i & 1] = __int_as_float(0x7f800000);  // +inf
        P4[p] = make_float4(v4.x, v4.y, v4.z, 0.0f);
    }
    float Bx = base[0], By = base[1], Bz = base[2];
    if (tid == 0) { cl[0] = Bx; cl[1] = By; cl[2] = Bz; }
    __syncthreads();  // P4 ready

    for (int k = 1; k < NGRP; ++k) {
        // ---- packed distance update, contraction OFF (exact RN mul/add) ----
        {
#pragma clang fp contract(off)
            const vf2 bx2 = {Bx, Bx}, by2 = {By, By}, bz2 = {Bz, Bz};
#pragma unroll
            for (int j = 0; j < 8; ++j) {
                const vf2 dx = px[j] - bx2;
                const vf2 dy = py[j] - by2;
                const vf2 dz = pz[j] - bz2;
                const vf2 mx2 = dx * dx;
                const vf2 my2 = dy * dy;
                const vf2 mz2 = dz * dz;
                const vf2 s = (mx2 + my2) + mz2;
                d2[j] = __builtin_elementwise_min(d2[j], s);  // v_pk_min_f32
            }
        }
        // ---- packed max tree ----
        vf2 mv = d2[0];
#pragma unroll
        for (int j = 1; j < 8; ++j) mv = __builtin_elementwise_max(mv, d2[j]);
        const float mx = fmaxf(mv[0], mv[1]);
        const float wmx = wave_max_f32(mx);
        // ---- lowest-slot recovery (slot i -> global idx i*512+tid, monotone) ----
        int wi = 0;
#pragma unroll
        for (int i = 15; i >= 1; --i) {
            wi = (d2[i >> 1][i & 1] == mx) ? i : wi;
        }
        // ---- wave winning index: ballot fast path, DPP-min fallback on ties ----
        unsigned widx_w;
        const unsigned long long bal = __ballot(mx == wmx);
        if (__popcll(bal) == 1) {  // wave-uniform branch
            const int L = __ffsll(bal) - 1;
            widx_w = (unsigned)(__builtin_amdgcn_readlane(wi, L) * 512 + (wv * 64 + L));
        } else {
            const unsigned cand = (mx == wmx) ? (unsigned)(wi * 512 + tid) : 0xFFFFFFFFu;
            widx_w = wave_min_u32(cand);
        }

        const int buf = k & 1;
        if ((tid & 63) == 0) {
            pkey[buf][wv] = __hiloint2double(__float_as_int(wmx), 8191 - (int)widx_w);
        }
        __syncthreads();  // LDS-only drain

        // ---- 7-fmax tree over 8 wave slots (4 x ds_read_b128) ----
        const double2* pp = reinterpret_cast<const double2*>(&pkey[buf][0]);
        const double2 a = pp[0], c = pp[1], e = pp[2], f = pp[3];
        const double g = fmax(fmax(fmax(a.x, a.y), fmax(c.x, c.y)),
                              fmax(fmax(e.x, e.y), fmax(f.x, f.y)));
        const int widx = 8191 - __double2loint(g);
        const float4 c4 = P4[widx];  // broadcast ds_read_b128
        Bx = c4.x; By = c4.y; Bz = c4.z;

        if (tid == 0) { cl[k * 3 + 0] = Bx; cl[k * 3 + 1] = By; cl[k * 3 + 2] = Bz; }
    }

    __syncthreads();
    float* cg = centers + (size_t)b * NGRP * 3;
    for (int t = tid; t < NGRP * 3; t += 512) cg[t] = cl[t];
}

// ---------------------------------------------------------------------------
// KNN + gather: one block (256 threads) per (batch, group) row.
// FP math byte-identical to the passing version. This round:
//  - float4 point loads (1 dwordx4 instead of 3 dwords; same values)
//  - lazy 2-deep cached min: keys never mutated; owner pops lm<-lm2, rescan
//    (min over key[i] > gm) only when lm2 invalid. Exact: selection ascending
//    + unique keys => remaining-min == min over keys strictly greater than gm.
//  - ballot shortcut for the lo-word chain when the hi-word min is unique.
// ---------------------------------------------------------------------------
__global__ __launch_bounds__(256) void knn_kernel(const float* __restrict__ xyz,
                                                  const float* __restrict__ centers,
                                                  float* __restrict__ neigh,
                                                  float* __restrict__ neigh_n) {
    const int row = blockIdx.x;   // b*NGRP + g
    const int b = row >> 9;
    const int tid = threadIdx.x;
    const int lane = tid & 63;
    const int wv = tid >> 6;  // 0..3

    __shared__ unsigned long long rk[2][4];
    __shared__ int sel[GSZ];

    const float* cptr = centers + (size_t)row * 3;
    const float cx = cptr[0], cy = cptr[1], cz = cptr[2];
    const float c2 = sq3(cx, cy, cz);

    const float* base = xyz + (size_t)b * NPTS * 6;
    unsigned long long key[32];
#pragma unroll
    for (int i = 0; i < 32; ++i) {
        const int p = i * 256 + tid;
        const float4 v4 = *reinterpret_cast<const float4*>(base + (size_t)p * 6);
        const float x = v4.x, y = v4.y, z = v4.z;
        const float x2 = sq3(x, y, z);
        // GEMM-style FMA accumulation over k = x,y,z
        const float dot = __fmaf_rn(cz, z, __fmaf_rn(cy, y, __fmul_rn(cx, x)));
        const float d2 = __fadd_rn(__fsub_rn(c2, __fmul_rn(2.0f, dot)), x2);
        // monotonic float->uint transform (3 instr form; bit-identical result)
        unsigned u = __float_as_uint(d2);
        u ^= (unsigned)(((int)u >> 31)) | 0x80000000u;
        key[i] = ((unsigned long long)u << 32) | (unsigned)p;
    }

    // 2-deep cached mins over this thread's 32 keys (keys unique, never 0)
    unsigned long long lm = ~0ULL, lm2v = ~0ULL;
#pragma unroll
    for (int i = 0; i < 32; ++i) {
        const unsigned long long kk = key[i];
        const bool a = kk < lm;
        const bool b2 = kk < lm2v;
        lm2v = a ? lm : (b2 ? kk : lm2v);
        lm = a ? kk : lm;
    }

    for (int r = 0; r < GSZ; ++r) {
        // ---- wave u64 min: hi chain + ballot shortcut for lo ----
        const unsigned hi = (unsigned)(lm >> 32);
        const unsigned minhi = wave_min_u32(hi);
        unsigned minlo;
        const unsigned long long bal = __ballot(hi == minhi);
        if (__popcll(bal) == 1) {  // wave-uniform branch
            const int L = __ffsll(bal) - 1;
            minlo = (unsigned)__builtin_amdgcn_readlane((int)(unsigned)lm, L);
        } else {
            const unsigned cand = (hi == minhi) ? (unsigned)lm : 0xFFFFFFFFu;
            minlo = wave_min_u32(cand);
        }
        const unsigned long long mk = ((unsigned long long)minhi << 32) | minlo;

        const int rb = r & 1;
        if (lane == 0) rk[rb][wv] = mk;
        __syncthreads();
        const ulonglong2* rp = reinterpret_cast<const ulonglong2*>(&rk[rb][0]);
        const ulonglong2 r0 = rp[0], r1 = rp[1];
        const unsigned long long g01 = r0.x < r0.y ? r0.x : r0.y;
        const unsigned long long g23 = r1.x < r1.y ? r1.x : r1.y;
        const unsigned long long gm = g01 < g23 ? g01 : g23;
        if (tid == 0) sel[r] = (int)(unsigned)(gm & 0xffffffffu);
        if (lm == gm) {  // unique owner pops
            if (lm2v != 0ULL) {
                lm = lm2v;
            } else {
                unsigned long long nm = ~0ULL;
#pragma unroll
                for (int i = 0; i < 32; ++i) {
                    const unsigned long long v = key[i] > gm ? key[i] : ~0ULL;
                    nm = v < nm ? v : nm;
                }
                lm = nm;
            }
            lm2v = 0ULL;  // invalidate (0 is never a valid key)
        }
    }
    __syncthreads();

    if (tid < GSZ) {
        const int idx = sel[tid];
        const float* q = base + (size_t)idx * 6;
        const float4 a4 = *reinterpret_cast<const float4*>(q);      // x,y,z,nx
        const float2 b2v = *reinterpret_cast<const float2*>(q + 4); // ny,nz
        const size_t o = ((size_t)row * GSZ + tid) * 3;
        neigh[o + 0] = __fsub_rn(a4.x, cx);
        neigh[o + 1] = __fsub_rn(a4.y, cy);
        neigh[o + 2] = __fsub_rn(a4.z, cz);
        neigh_n[o + 0] = a4.w;
        neigh_n[o + 1] = b2v.x;
        neigh_n[o + 2] = b2v.y;
    }
}

extern "C" void kernel_launch(void* const* d_in, const int* in_sizes, int n_in,
                              void* d_out, int out_size, void* d_ws, size_t ws_size,
                              hipStream_t stream) {
    const float* xyz = (const float*)d_in[0];
    float* out = (float*)d_out;
    float* neigh   = out;                                   // [8,512,32,3]
    float* neigh_n = out + (size_t)BATCH * NGRP * GSZ * 3;  // [8,512,32,3]
    float* centers = out + (size_t)2 * BATCH * NGRP * GSZ * 3;  // [8,512,3]

    fps_kernel<<<BATCH, 512, 0, stream>>>(xyz, centers);
    knn_kernel<<<BATCH * NGRP, 256, 0, stream>>>(xyz, centers, neigh, neigh_n);
}